// Round 9
// baseline (144.776 us; speedup 1.0000x reference)
//
#include <hip/hip_runtime.h>
#include <stdint.h>

#define NB_ 8
#define NC_ 128
#define NN_ 4096

typedef float f32x4 __attribute__((ext_vector_type(4)));
typedef _Float16 f16x8 __attribute__((ext_vector_type(8)));
typedef short s16x8 __attribute__((ext_vector_type(8)));

__device__ __forceinline__ uint16_t f2bf(float f) {
    union { float f; uint32_t u; } v; v.f = f;
    return (uint16_t)((v.u + 0x7FFFu + ((v.u >> 16) & 1u)) >> 16);
}

// ---------------- prep: build xt = fp16 x^T [N][C], xv = bf16 x [C][N] ----
__global__ __launch_bounds__(256) void prep_kernel(
        const float* __restrict__ pts, _Float16* __restrict__ xt,
        uint16_t* __restrict__ xv) {
    __shared__ float T[64][65];
    int bid = blockIdx.x;
    int ct = bid & 1, nt = (bid >> 1) & 63, b = bid >> 7;
    int c0 = ct * 64, n0 = nt * 64;
    int lr = threadIdx.x >> 6, lc = threadIdx.x & 63;
    const float* src = pts + ((size_t)b * NC_ + c0) * NN_ + n0;
#pragma unroll
    for (int r = 0; r < 16; ++r) {
        int cl = r * 4 + lr;
        float v = src[(size_t)cl * NN_ + lc];
        T[cl][lc] = v;
        xv[((size_t)b * NC_ + c0 + cl) * NN_ + n0 + lc] = f2bf(v);
    }
    __syncthreads();
#pragma unroll
    for (int r = 0; r < 16; ++r) {
        int nl = r * 4 + lr;
        xt[((size_t)b * NN_ + n0 + nl) * NC_ + c0 + lc] = (_Float16)T[lc][nl];
    }
}

// ---------------- flash: fused QK^T -> exp -> PV, fixed shift 64 ----------
// 4 waves x 32 n-cols (best LDS-bytes-per-MFMA ratio). K/V double-buffered
// in LDS, ONE barrier per iter. K staged by global_load_lds (LDS-linear dst,
// pre-swizzled global source so reads keep chunk^(row&7)). V reg-staged with
// 80B-padded rows. ~160 unified regs + 46.5KB LDS -> 3 blocks/CU naturally
// (no launch_bounds cap -> no spill risk). XCD-pinned b = bid & 7.
template <int MSPLIT>
__global__ __launch_bounds__(256) void flash_kernel(
        const _Float16* __restrict__ xt, const uint16_t* __restrict__ xv,
        float* __restrict__ Opart, float* __restrict__ lpart,
        const float* __restrict__ pts, const float* __restrict__ gamma,
        float* __restrict__ out) {
    int bid = blockIdx.x;
    int b = bid & 7;
    int rest = bid >> 3;
    int nb = rest & 31;
    int mh = rest >> 5;          // 0..MSPLIT-1
    int tid = threadIdx.x;
    int w = tid >> 6, l = tid & 63, l15 = l & 15, g = l >> 4;

    __shared__ __align__(16) uint16_t Kt[2 * 32 * 128];  // dbuf, [row][chunk^(row&7)]
    __shared__ __align__(16) uint16_t Vt[2 * 128 * 40];  // dbuf, 80B row stride
    __shared__ __align__(16) uint16_t Plds[4][32][40];
    __shared__ float Lsh[4][32];

    int nbase = nb * 128 + w * 32;
    const _Float16* xtb = xt + (size_t)b * NN_ * NC_;
    const uint16_t* xvb = xv + (size_t)b * NC_ * NN_;

    // --- K staging via global_load_lds: wave w covers rows w*8..w*8+7 (2 calls)
    // lane l writes LDS slot (row = seg*4 + l>>4, slot16 = l&15); the data that
    // must land there is global chunk (slot ^ (row&7))  [pre-swizzled source].
    int krow0 = (w * 2 + 0) * 4 + (l >> 4);
    int krow1 = (w * 2 + 1) * 4 + (l >> 4);
    int koff0 = krow0 * 256 + (((l & 15) ^ (krow0 & 7)) * 16);  // bytes
    int koff1 = krow1 * 256 + (((l & 15) ^ (krow1 & 7)) * 16);
    int ksegB = __builtin_amdgcn_readfirstlane(w) * 2048;       // wave's 2KB base

#define K_GLL(M0ROW, BUF) do {                                                         \
        const char* gk_ = (const char*)xtb + (size_t)(M0ROW) * 256;                    \
        char* lk_ = (char*)Kt + (BUF) * 8192 + ksegB;                                  \
        __builtin_amdgcn_global_load_lds(                                              \
            (const __attribute__((address_space(1))) void*)(gk_ + koff0),              \
            (__attribute__((address_space(3))) void*)lk_, 16, 0, 0);                   \
        __builtin_amdgcn_global_load_lds(                                              \
            (const __attribute__((address_space(1))) void*)(gk_ + koff1),              \
            (__attribute__((address_space(3))) void*)(lk_ + 1024), 16, 0, 0);          \
    } while (0)

    // --- V staging (reg path, 80B-pad preserved): 256 thr x 32B
    int vRow = tid >> 1, vC = (tid & 1) * 16;
    const uint16_t* vSrcB = xvb + (size_t)vRow * NN_ + vC;

    // Q fragments: A[row=n][k=c], lane: row = l15, k = g*8+j  (k-chunks of 32)
    f16x8 q[2][4];
#pragma unroll
    for (int ns = 0; ns < 2; ++ns)
#pragma unroll
        for (int cc = 0; cc < 4; ++cc)
            q[ns][cc] = *(const f16x8*)(xtb + (size_t)(nbase + ns * 16 + l15) * NC_ + cc * 32 + g * 8);

    f32x4 acc[8][2];
#pragma unroll
    for (int cs = 0; cs < 8; ++cs)
#pragma unroll
        for (int ns = 0; ns < 2; ++ns)
            acc[cs][ns] = (f32x4){0.f, 0.f, 0.f, 0.f};
    float lsum[2][4] = {{0.f, 0.f, 0.f, 0.f}, {0.f, 0.f, 0.f, 0.f}};

    const int nsteps = (MSPLIT == 3) ? (mh < 2 ? 43 : 42) : (128 / MSPLIT);
    const int mstart = (MSPLIT == 3) ? (mh * 43 * 32) : (mh * (128 / MSPLIT) * 32);

    int krx = l15 & 7;

    // prologue: stage tile 0 into buffer 0
    K_GLL(mstart, 0);
    s16x8 vn0 = *(const s16x8*)(vSrcB + mstart);
    s16x8 vn1 = *(const s16x8*)(vSrcB + mstart + 8);
    {
        uint16_t* vd = Vt + vRow * 40 + vC;
        *(s16x8*)vd = vn0;
        *(s16x8*)(vd + 8) = vn1;
    }

    for (int it = 0; it < nsteps; ++it) {
        __syncthreads();   // drains vmcnt (K gll landed) + lgkm (V writes visible);
                           // also: all waves done reading the other buffer.
        int cur = it & 1, nxt = cur ^ 1;
        int m0 = mstart + it * 32;
        bool more = (it + 1) < nsteps;
        if (more) {
            K_GLL(m0 + 32, nxt);
            vn0 = *(const s16x8*)(vSrcB + m0 + 32);
            vn1 = *(const s16x8*)(vSrcB + m0 + 40);
        }

        const _Float16* Kc = (const _Float16*)Kt + cur * 4096;
        const uint16_t* Vc = Vt + cur * 5120;

        // QK per ms-half: load kf (streamed), 8 MFMAs, exp+P-write immediately
#pragma unroll
        for (int ms = 0; ms < 2; ++ms) {
            f16x8 kf[4];
#pragma unroll
            for (int cc = 0; cc < 4; ++cc)
                kf[cc] = *(const f16x8*)(Kc + (ms * 16 + l15) * 128 + (((cc * 4 + g) ^ krx) * 8));
            f32x4 s0 = (f32x4){0.f, 0.f, 0.f, 0.f};
            f32x4 s1 = (f32x4){0.f, 0.f, 0.f, 0.f};
            __builtin_amdgcn_s_setprio(1);
#pragma unroll
            for (int cc = 0; cc < 4; ++cc) {
                s0 = __builtin_amdgcn_mfma_f32_16x16x32_f16(q[0][cc], kf[cc], s0, 0, 0, 0);
                s1 = __builtin_amdgcn_mfma_f32_16x16x32_f16(q[1][cc], kf[cc], s1, 0, 0, 0);
            }
            __builtin_amdgcn_s_setprio(0);
            // P = exp(-(S+64)); C/D layout: row n = g*4+r, col m = l15.
#pragma unroll
            for (int r = 0; r < 4; ++r) {
                float p0 = __expf(-(s0[r] + 64.f));
                float p1 = __expf(-(s1[r] + 64.f));
                lsum[0][r] += p0;
                lsum[1][r] += p1;
                Plds[w][g * 4 + r][ms * 16 + l15] = f2bf(p0);
                Plds[w][16 + g * 4 + r][ms * 16 + l15] = f2bf(p1);
            }
        }
        asm volatile("s_waitcnt lgkmcnt(0)" ::: "memory");

        // P^T fragments for PV: B[k=m][col=n], lane: col = l15, k = g*8+j
        s16x8 pf[2];
#pragma unroll
        for (int ns = 0; ns < 2; ++ns)
            pf[ns] = *(const s16x8*)&Plds[w][ns * 16 + l15][g * 8];

        // O[c][n] += V[c][m] * P^T[m][n]; V frag from LDS: A[row=c][k=m]
        __builtin_amdgcn_s_setprio(1);
#pragma unroll
        for (int cs = 0; cs < 8; ++cs) {
            s16x8 vf = *(const s16x8*)(Vc + (cs * 16 + l15) * 40 + g * 8);
#pragma unroll
            for (int ns = 0; ns < 2; ++ns)
                acc[cs][ns] = __builtin_amdgcn_mfma_f32_16x16x32_bf16(vf, pf[ns], acc[cs][ns], 0, 0, 0);
        }
        __builtin_amdgcn_s_setprio(0);

        if (more) {
            uint16_t* vd = Vt + nxt * 5120 + vRow * 40 + vC;
            *(s16x8*)vd = vn0;
            *(s16x8*)(vd + 8) = vn1;
        }
    }
#undef K_GLL

    // reduce lsum over the 16 lanes of each lane-group (cols m of the S tile)
#pragma unroll
    for (int ns = 0; ns < 2; ++ns)
#pragma unroll
        for (int r = 0; r < 4; ++r) {
            float v2 = lsum[ns][r];
            v2 += __shfl_xor(v2, 1, 16);
            v2 += __shfl_xor(v2, 2, 16);
            v2 += __shfl_xor(v2, 4, 16);
            v2 += __shfl_xor(v2, 8, 16);
            lsum[ns][r] = v2;
        }

    if (MSPLIT > 1) {
        size_t obase = (size_t)((b * 32 + nb) * MSPLIT + mh) * (128 * 128);
#pragma unroll
        for (int cs = 0; cs < 8; ++cs)
#pragma unroll
            for (int ns = 0; ns < 2; ++ns)
#pragma unroll
                for (int r = 0; r < 4; ++r)
                    Opart[obase + (size_t)(cs * 16 + g * 4 + r) * 128 + w * 32 + ns * 16 + l15] =
                        acc[cs][ns][r];
        if (l15 == 0) {
            size_t lb = (size_t)((b * 32 + nb) * MSPLIT + mh) * 128;
#pragma unroll
            for (int ns = 0; ns < 2; ++ns)
#pragma unroll
                for (int r = 0; r < 4; ++r)
                    lpart[lb + w * 32 + ns * 16 + g * 4 + r] = lsum[ns][r];
        }
    } else {
        if (l15 == 0) {
#pragma unroll
            for (int ns = 0; ns < 2; ++ns)
#pragma unroll
                for (int r = 0; r < 4; ++r)
                    Lsh[w][ns * 16 + g * 4 + r] = lsum[ns][r];
        }
        __syncthreads();
        float gm = gamma[0];
        float linv[2];
#pragma unroll
        for (int ns = 0; ns < 2; ++ns) linv[ns] = 1.0f / Lsh[w][ns * 16 + l15];
        const float* ptsb = pts + (size_t)b * NC_ * NN_;
        float* outb = out + (size_t)b * NC_ * NN_;
#pragma unroll
        for (int cs = 0; cs < 8; ++cs)
#pragma unroll
            for (int ns = 0; ns < 2; ++ns)
#pragma unroll
                for (int r = 0; r < 4; ++r) {
                    size_t idx = (size_t)(cs * 16 + g * 4 + r) * NN_ + nbase + ns * 16 + l15;
                    outb[idx] = gm * acc[cs][ns][r] * linv[ns] + ptsb[idx];
                }
    }
}

// ---------------- epilogue: out = gamma * (sum O_i) / (sum l_i) + pts -----
template <int NS>
__global__ __launch_bounds__(256) void epi_kernel(
        const float* __restrict__ pts, const float* __restrict__ gamma,
        const float* __restrict__ Opart, const float* __restrict__ lpart,
        float* __restrict__ out) {
    size_t t = (size_t)blockIdx.x * 256 + threadIdx.x;
    size_t e = t * 4;
    int b = (int)(e >> 19);           // / (128*4096)
    int r = (int)(e & 524287);
    int c = r >> 12;
    int n = r & 4095;
    int nb = n >> 7, nl = n & 127;
    size_t ob = (size_t)((b * 32 + nb) * NS) * 16384 + (size_t)c * 128 + nl;
    size_t lb = (size_t)((b * 32 + nb) * NS) * 128 + nl;
    f32x4 osum = (f32x4){0.f, 0.f, 0.f, 0.f};
    f32x4 lsum = (f32x4){0.f, 0.f, 0.f, 0.f};
#pragma unroll
    for (int i = 0; i < NS; ++i) {
        f32x4 o = *(const f32x4*)(Opart + ob + (size_t)i * 16384);
        f32x4 li = *(const f32x4*)(lpart + lb + (size_t)i * 128);
#pragma unroll
        for (int j = 0; j < 4; ++j) { osum[j] += o[j]; lsum[j] += li[j]; }
    }
    f32x4 p = *(const f32x4*)(pts + e);
    float gm = gamma[0];
    f32x4 res;
#pragma unroll
    for (int j = 0; j < 4; ++j)
        res[j] = gm * osum[j] / lsum[j] + p[j];
    *(f32x4*)(out + e) = res;
}

extern "C" void kernel_launch(void* const* d_in, const int* in_sizes, int n_in,
                              void* d_out, int out_size, void* d_ws, size_t ws_size,
                              hipStream_t stream) {
    const float* pts = (const float*)d_in[0];
    const float* gamma = (const float*)d_in[1];
    float* out = (float*)d_out;

    char* ws = (char*)d_ws;
    _Float16* xt = (_Float16*)ws;                              // 8 MB
    uint16_t* xv = (uint16_t*)(ws + 8388608);                  // 8 MB
    float* Opart = (float*)(ws + 16777216);                    // 48 MB (msplit3)
    const size_t WS3 = 16777216ull + 50331648ull + 393216ull;  // 64.4 MB

    prep_kernel<<<1024, 256, 0, stream>>>(pts, xt, xv);
    if (ws_size >= WS3) {
        float* lpart = (float*)(ws + 16777216 + 50331648);
        flash_kernel<3><<<768, 256, 0, stream>>>(xt, xv, Opart, lpart, pts, gamma, out);
        epi_kernel<3><<<4096, 256, 0, stream>>>(pts, gamma, Opart, lpart, out);
    } else {
        flash_kernel<1><<<256, 256, 0, stream>>>(xt, xv, nullptr, nullptr, pts, gamma, out);
    }
}

// Round 10
// 108.036 us; speedup vs baseline: 1.3401x; 1.3401x over previous
//
#include <hip/hip_runtime.h>
#include <stdint.h>

#define NB_ 8
#define NC_ 128
#define NN_ 4096

typedef float f32x4 __attribute__((ext_vector_type(4)));
typedef _Float16 f16x8 __attribute__((ext_vector_type(8)));
typedef short s16x8 __attribute__((ext_vector_type(8)));

__device__ __forceinline__ uint16_t f2bf(float f) {
    union { float f; uint32_t u; } v; v.f = f;
    return (uint16_t)((v.u + 0x7FFFu + ((v.u >> 16) & 1u)) >> 16);
}
// P >= 0 (exp output): truncation is safe; down-bias cancels in O/l ratio.
__device__ __forceinline__ uint16_t f2bf_trunc(float f) {
    union { float f; uint32_t u; } v; v.f = f;
    return (uint16_t)(v.u >> 16);
}

// ---------------- prep: build xt = fp16 x^T [N][C], xv = bf16 x [C][N] ----
__global__ __launch_bounds__(256) void prep_kernel(
        const float* __restrict__ pts, _Float16* __restrict__ xt,
        uint16_t* __restrict__ xv) {
    __shared__ float T[64][65];
    int bid = blockIdx.x;
    int ct = bid & 1, nt = (bid >> 1) & 63, b = bid >> 7;
    int c0 = ct * 64, n0 = nt * 64;
    int lr = threadIdx.x >> 6, lc = threadIdx.x & 63;
    const float* src = pts + ((size_t)b * NC_ + c0) * NN_ + n0;
#pragma unroll
    for (int r = 0; r < 16; ++r) {
        int cl = r * 4 + lr;
        float v = src[(size_t)cl * NN_ + lc];
        T[cl][lc] = v;
        xv[((size_t)b * NC_ + c0 + cl) * NN_ + n0 + lc] = f2bf(v);
    }
    __syncthreads();
#pragma unroll
    for (int r = 0; r < 16; ++r) {
        int nl = r * 4 + lr;
        xt[((size_t)b * NN_ + n0 + nl) * NC_ + c0 + lc] = (_Float16)T[lc][nl];
    }
}

// ---------------- flash: fused QK^T -> exp -> PV, fixed shift 64 ----------
// R4 structure (proven 108us): single-buffer K/V LDS tiles, 2 barriers/iter,
// reg-staged K (XOR swizzle chunk^(row&7)) and V (80B rows), prefetch issued
// at top of iter. Shaves for 3 blocks/CU: kf streamed per-ms (-16 VGPR),
// P stored via truncation (-~48 VALU/iter). launch_bounds(256,3): cap 170
// fits ~156-160 unified demand. msplit3 grid 768 = exactly 3 blocks/CU.
template <int MSPLIT>
__global__ __launch_bounds__(256, 3) void flash_kernel(
        const _Float16* __restrict__ xt, const uint16_t* __restrict__ xv,
        float* __restrict__ Opart, float* __restrict__ lpart,
        const float* __restrict__ pts, const float* __restrict__ gamma,
        float* __restrict__ out) {
    int bid = blockIdx.x;
    int b = bid & 7;
    int rest = bid >> 3;
    int nb = rest & 31;
    int mh = rest >> 5;          // 0..MSPLIT-1
    int tid = threadIdx.x;
    int w = tid >> 6, l = tid & 63, l15 = l & 15, g = l >> 4;

    __shared__ __align__(16) uint16_t Kt[32 * 128];   // fp16 bits, [row][chunk^(row&7)]
    __shared__ __align__(16) uint16_t Vt[128 * 40];   // bf16, 80B row stride
    __shared__ __align__(16) uint16_t Plds[4][32][40];
    __shared__ float Lsh[4][32];

    int nbase = nb * 128 + w * 32;
    const _Float16* xtb = xt + (size_t)b * NN_ * NC_;
    const uint16_t* xvb = xv + (size_t)b * NC_ * NN_;

    // staging assignment (256 threads, 16 KB/iter)
    int kRow = tid >> 3, kC2 = (tid & 7) * 2;      // K: row 0..31, 2 chunks of 8 f16
    int vRow = tid >> 1, vC = (tid & 1) * 16;      // V: row 0..127, 16 bf16
    const uint16_t* kSrcB = (const uint16_t*)xtb + (size_t)kRow * NC_ + kC2 * 8;
    const uint16_t* vSrcB = xvb + (size_t)vRow * NN_ + vC;
    uint16_t* kDstA = Kt + kRow * 128 + ((kC2 ^ (kRow & 7)) * 8);
    uint16_t* kDstB = Kt + kRow * 128 + (((kC2 + 1) ^ (kRow & 7)) * 8);
    uint16_t* vDst = Vt + vRow * 40 + vC;

    // Q fragments: A[row=n][k=c], lane: row = l15, k = g*8+j  (k-chunks of 32)
    f16x8 q[2][4];
#pragma unroll
    for (int ns = 0; ns < 2; ++ns)
#pragma unroll
        for (int cc = 0; cc < 4; ++cc)
            q[ns][cc] = *(const f16x8*)(xtb + (size_t)(nbase + ns * 16 + l15) * NC_ + cc * 32 + g * 8);

    f32x4 acc[8][2];
#pragma unroll
    for (int cs = 0; cs < 8; ++cs)
#pragma unroll
        for (int ns = 0; ns < 2; ++ns)
            acc[cs][ns] = (f32x4){0.f, 0.f, 0.f, 0.f};
    float lsum[2][4] = {{0.f, 0.f, 0.f, 0.f}, {0.f, 0.f, 0.f, 0.f}};

    const int nsteps = (MSPLIT == 3) ? (mh < 2 ? 43 : 42) : (128 / MSPLIT);
    const int mstart = (MSPLIT == 3) ? (mh * 43 * 32) : (mh * (128 / MSPLIT) * 32);

    // prologue: stage tile 0
    s16x8 kn0 = *(const s16x8*)(kSrcB + (size_t)mstart * NC_);
    s16x8 kn1 = *(const s16x8*)(kSrcB + (size_t)mstart * NC_ + 8);
    s16x8 vn0 = *(const s16x8*)(vSrcB + mstart);
    s16x8 vn1 = *(const s16x8*)(vSrcB + mstart + 8);
    *(s16x8*)kDstA = kn0;
    *(s16x8*)kDstB = kn1;
    *(s16x8*)vDst = vn0;
    *(s16x8*)(vDst + 8) = vn1;
    __syncthreads();

    int krx = l15 & 7;

    for (int it = 0; it < nsteps; ++it) {
        int m0 = mstart + it * 32;
        bool more = (it + 1) < nsteps;
        // issue next tile's global loads early (written after barrier #1)
        if (more) {
            int m1 = m0 + 32;
            kn0 = *(const s16x8*)(kSrcB + (size_t)m1 * NC_);
            kn1 = *(const s16x8*)(kSrcB + (size_t)m1 * NC_ + 8);
            vn0 = *(const s16x8*)(vSrcB + m1);
            vn1 = *(const s16x8*)(vSrcB + m1 + 8);
        }

        // QK per ms-half: stream kf (16 live regs), 8 MFMAs, exp + P-store
#pragma unroll
        for (int ms = 0; ms < 2; ++ms) {
            f16x8 kf[4];
#pragma unroll
            for (int cc = 0; cc < 4; ++cc)
                kf[cc] = *(const f16x8*)(Kt + (ms * 16 + l15) * 128 + (((cc * 4 + g) ^ krx) * 8));
            f32x4 s0 = (f32x4){0.f, 0.f, 0.f, 0.f};
            f32x4 s1 = (f32x4){0.f, 0.f, 0.f, 0.f};
            __builtin_amdgcn_s_setprio(1);
#pragma unroll
            for (int cc = 0; cc < 4; ++cc) {
                s0 = __builtin_amdgcn_mfma_f32_16x16x32_f16(q[0][cc], kf[cc], s0, 0, 0, 0);
                s1 = __builtin_amdgcn_mfma_f32_16x16x32_f16(q[1][cc], kf[cc], s1, 0, 0, 0);
            }
            __builtin_amdgcn_s_setprio(0);
            // P = exp(-(S+64)); C/D layout: row n = g*4+r, col m = l15.
#pragma unroll
            for (int r = 0; r < 4; ++r) {
                float p0 = __expf(-(s0[r] + 64.f));
                float p1 = __expf(-(s1[r] + 64.f));
                lsum[0][r] += p0;
                lsum[1][r] += p1;
                Plds[w][g * 4 + r][ms * 16 + l15] = f2bf_trunc(p0);
                Plds[w][16 + g * 4 + r][ms * 16 + l15] = f2bf_trunc(p1);
            }
        }
        asm volatile("s_waitcnt lgkmcnt(0)" ::: "memory");

        // P^T fragments for PV: B[k=m][col=n], lane: col = l15, k = g*8+j
        s16x8 pf[2];
#pragma unroll
        for (int ns = 0; ns < 2; ++ns)
            pf[ns] = *(const s16x8*)&Plds[w][ns * 16 + l15][g * 8];

        // O[c][n] += V[c][m] * P^T[m][n]; V frag from LDS: A[row=c][k=m]
        __builtin_amdgcn_s_setprio(1);
#pragma unroll
        for (int cs = 0; cs < 8; ++cs) {
            s16x8 vf = *(const s16x8*)(Vt + (cs * 16 + l15) * 40 + g * 8);
#pragma unroll
            for (int ns = 0; ns < 2; ++ns)
                acc[cs][ns] = __builtin_amdgcn_mfma_f32_16x16x32_bf16(vf, pf[ns], acc[cs][ns], 0, 0, 0);
        }
        __builtin_amdgcn_s_setprio(0);

        __syncthreads();   // all waves done reading current tile
        if (more) {
            *(s16x8*)kDstA = kn0;
            *(s16x8*)kDstB = kn1;
            *(s16x8*)vDst = vn0;
            *(s16x8*)(vDst + 8) = vn1;
        }
        __syncthreads();   // new tile visible
    }

    // reduce lsum over the 16 lanes of each lane-group (cols m of the S tile)
#pragma unroll
    for (int ns = 0; ns < 2; ++ns)
#pragma unroll
        for (int r = 0; r < 4; ++r) {
            float v2 = lsum[ns][r];
            v2 += __shfl_xor(v2, 1, 16);
            v2 += __shfl_xor(v2, 2, 16);
            v2 += __shfl_xor(v2, 4, 16);
            v2 += __shfl_xor(v2, 8, 16);
            lsum[ns][r] = v2;
        }

    if (MSPLIT > 1) {
        size_t obase = (size_t)((b * 32 + nb) * MSPLIT + mh) * (128 * 128);
#pragma unroll
        for (int cs = 0; cs < 8; ++cs)
#pragma unroll
            for (int ns = 0; ns < 2; ++ns)
#pragma unroll
                for (int r = 0; r < 4; ++r)
                    Opart[obase + (size_t)(cs * 16 + g * 4 + r) * 128 + w * 32 + ns * 16 + l15] =
                        acc[cs][ns][r];
        if (l15 == 0) {
            size_t lb = (size_t)((b * 32 + nb) * MSPLIT + mh) * 128;
#pragma unroll
            for (int ns = 0; ns < 2; ++ns)
#pragma unroll
                for (int r = 0; r < 4; ++r)
                    lpart[lb + w * 32 + ns * 16 + g * 4 + r] = lsum[ns][r];
        }
    } else {
        if (l15 == 0) {
#pragma unroll
            for (int ns = 0; ns < 2; ++ns)
#pragma unroll
                for (int r = 0; r < 4; ++r)
                    Lsh[w][ns * 16 + g * 4 + r] = lsum[ns][r];
        }
        __syncthreads();
        float gm = gamma[0];
        float linv[2];
#pragma unroll
        for (int ns = 0; ns < 2; ++ns) linv[ns] = 1.0f / Lsh[w][ns * 16 + l15];
        const float* ptsb = pts + (size_t)b * NC_ * NN_;
        float* outb = out + (size_t)b * NC_ * NN_;
#pragma unroll
        for (int cs = 0; cs < 8; ++cs)
#pragma unroll
            for (int ns = 0; ns < 2; ++ns)
#pragma unroll
                for (int r = 0; r < 4; ++r) {
                    size_t idx = (size_t)(cs * 16 + g * 4 + r) * NN_ + nbase + ns * 16 + l15;
                    outb[idx] = gm * acc[cs][ns][r] * linv[ns] + ptsb[idx];
                }
    }
}

// ---------------- epilogue: out = gamma * (sum O_i) / (sum l_i) + pts -----
template <int NS>
__global__ __launch_bounds__(256) void epi_kernel(
        const float* __restrict__ pts, const float* __restrict__ gamma,
        const float* __restrict__ Opart, const float* __restrict__ lpart,
        float* __restrict__ out) {
    size_t t = (size_t)blockIdx.x * 256 + threadIdx.x;
    size_t e = t * 4;
    int b = (int)(e >> 19);           // / (128*4096)
    int r = (int)(e & 524287);
    int c = r >> 12;
    int n = r & 4095;
    int nb = n >> 7, nl = n & 127;
    size_t ob = (size_t)((b * 32 + nb) * NS) * 16384 + (size_t)c * 128 + nl;
    size_t lb = (size_t)((b * 32 + nb) * NS) * 128 + nl;
    f32x4 osum = (f32x4){0.f, 0.f, 0.f, 0.f};
    f32x4 lsum = (f32x4){0.f, 0.f, 0.f, 0.f};
#pragma unroll
    for (int i = 0; i < NS; ++i) {
        f32x4 o = *(const f32x4*)(Opart + ob + (size_t)i * 16384);
        f32x4 li = *(const f32x4*)(lpart + lb + (size_t)i * 128);
#pragma unroll
        for (int j = 0; j < 4; ++j) { osum[j] += o[j]; lsum[j] += li[j]; }
    }
    f32x4 p = *(const f32x4*)(pts + e);
    float gm = gamma[0];
    f32x4 res;
#pragma unroll
    for (int j = 0; j < 4; ++j)
        res[j] = gm * osum[j] / lsum[j] + p[j];
    *(f32x4*)(out + e) = res;
}

extern "C" void kernel_launch(void* const* d_in, const int* in_sizes, int n_in,
                              void* d_out, int out_size, void* d_ws, size_t ws_size,
                              hipStream_t stream) {
    const float* pts = (const float*)d_in[0];
    const float* gamma = (const float*)d_in[1];
    float* out = (float*)d_out;

    char* ws = (char*)d_ws;
    _Float16* xt = (_Float16*)ws;                              // 8 MB
    uint16_t* xv = (uint16_t*)(ws + 8388608);                  // 8 MB
    float* Opart = (float*)(ws + 16777216);                    // 48 MB (msplit3)
    const size_t WS3 = 16777216ull + 50331648ull + 393216ull;  // 64.4 MB

    prep_kernel<<<1024, 256, 0, stream>>>(pts, xt, xv);
    if (ws_size >= WS3) {
        float* lpart = (float*)(ws + 16777216 + 50331648);
        flash_kernel<3><<<768, 256, 0, stream>>>(xt, xv, Opart, lpart, pts, gamma, out);
        epi_kernel<3><<<4096, 256, 0, stream>>>(pts, gamma, Opart, lpart, out);
    } else {
        flash_kernel<1><<<256, 256, 0, stream>>>(xt, xv, nullptr, nullptr, pts, gamma, out);
    }
}